// Round 7
// baseline (113.824 us; speedup 1.0000x reference)
//
#include <hip/hip_runtime.h>

// BaseModel_3100966387783 — per-variable masked 3-layer MLP, b=8192, D=128, h=64, o=2.
//
// R7 = R6 with the f16x2 type fixed (__fp16 ext_vector(2), matching
// __builtin_amdgcn_cvt_pkrtz's return type).
//
// R6 design: R5 skeleton (bricks, register-resident w0/w1, transposed MFMA,
// VALU L2) on a REGISTER DIET to reach 3 waves/SIMD (R5 was ~220 regs/wave
// -> 2/SIMD, occupancy-bound):
//   - biases: per-iter global dwordx4 loads straight into MFMA C-operand
//     (loop-invariant address -> L1-hit; zero persistent regs)
//   - w2 as f16 pairs + v_dot2_f32_f16 (8 regs, 16 dot2 vs 32 fma)
//   - acc0/acc1 share one accumulator array; no cross-iter hf pipelining
//   - 256-thr blocks (4 waves x 16 rows), 8 KB LDS, zero barriers
// brick = 1 KB = 64 lanes x 16 B bf16; lane l holds
//   T[tile*16 + (l&15)][ks*32 + (l>>4)*8 + 0..7]  (one MFMA A/B fragment).

typedef __bf16 bf16_t;
typedef __bf16 bf16x8 __attribute__((ext_vector_type(8)));
typedef float  f32x4  __attribute__((ext_vector_type(4)));
typedef __fp16 f16x2  __attribute__((ext_vector_type(2)));

#define LEAKY 0.01f

// ---------------- ws brick regions (byte offsets) ----------------
#define XB_OFF   0u                  // x bricks:   512 row-tiles x 4 ks = 2048 bricks
#define W0B_OFF  (2048u*1024u)       // w0 masked: 128 t x 4 it x 4 ks = 2048
#define W1B_OFF  (4096u*1024u)       // w1:        128 t x 4 it x 2 ks = 1024
// total ws need: 5120 KiB

// =================== pre-kernel: fp32 -> bf16 brick-ify ===================
__global__ __launch_bounds__(256)
void brickify(const float* __restrict__ x,  const float* __restrict__ w0,
              const float* __restrict__ w1, unsigned char* __restrict__ ws)
{
    const int wid  = blockIdx.x * 4 + (threadIdx.x >> 6);  // one wave = one brick
    const int lane = threadIdx.x & 63;
    const int lr = lane & 15, lq = lane >> 4;

    float v[8];
    if (wid < 2048) {                        // ---- x bricks ----
        int bt = wid >> 5, rem = wid & 31, nt = rem >> 2, ks = rem & 3;
        const float* s = x + (size_t)(bt*128 + nt*16 + lr) * 128 + ks*32 + lq*8;
        const float4 a = *(const float4*)s, b = *(const float4*)(s + 4);
        v[0]=a.x; v[1]=a.y; v[2]=a.z; v[3]=a.w;
        v[4]=b.x; v[5]=b.y; v[6]=b.z; v[7]=b.w;
    } else if (wid < 4096) {                 // ---- w0 bricks (masked j==t -> 0) ----
        int u = wid - 2048, t = u >> 4, rem = u & 15, it = rem >> 2, ks = rem & 3;
        int k0 = ks*32 + lq*8;
        const float* s = w0 + (size_t)(t*64 + it*16 + lr) * 128 + k0;
        const float4 a = *(const float4*)s, b = *(const float4*)(s + 4);
        v[0]=a.x; v[1]=a.y; v[2]=a.z; v[3]=a.w;
        v[4]=b.x; v[5]=b.y; v[6]=b.z; v[7]=b.w;
        #pragma unroll
        for (int j = 0; j < 8; ++j) if (k0 + j == t) v[j] = 0.f;
    } else {                                 // ---- w1 bricks ----
        int u = wid - 4096, t = u >> 3, rem = u & 7, it = rem >> 1, ks = rem & 1;
        const float* s = w1 + (size_t)(t*64 + it*16 + lr) * 64 + ks*32 + lq*8;
        const float4 a = *(const float4*)s, b = *(const float4*)(s + 4);
        v[0]=a.x; v[1]=a.y; v[2]=a.z; v[3]=a.w;
        v[4]=b.x; v[5]=b.y; v[6]=b.z; v[7]=b.w;
    }
    union { bf16_t h[8]; uint4 q; } pk;
    #pragma unroll
    for (int j = 0; j < 8; ++j) pk.h[j] = (bf16_t)v[j];
    ((uint4*)ws)[(size_t)wid * 64 + lane] = pk.q;   // dst = brick*1024 + lane*16
}

// =========================== main fused kernel ===========================
__global__ __launch_bounds__(256, 3)
void fused_mlp(const unsigned char* __restrict__ ws,
               const float* __restrict__ w2,
               const float* __restrict__ b0, const float* __restrict__ b1,
               const float* __restrict__ b2, float* __restrict__ out)
{
    // h bricks: 4 waves x 2 bricks, wave-private, single-buffered. No barriers.
    __shared__ __align__(16) unsigned char hsm[8192];

    const int tid  = threadIdx.x;
    const int w    = tid >> 6;         // wave 0..3
    const int lane = tid & 63;
    const int lr = lane & 15, lq = lane >> 4;
    const int g  = blockIdx.x;         // batch super-group: rows g*512 .. g*512+511
    const int t  = blockIdx.y;         // variable index

    // ---- w0/w1 fragments: global -> registers (L2-hit, 1 KB/instr) ----
    const unsigned char* w0p = ws + W0B_OFF + (size_t)t*16384 + lane*16;
    const unsigned char* w1p = ws + W1B_OFF + (size_t)t*8192  + lane*16;
    bf16x8 w0f[4][4], w1f[4][2];
    #pragma unroll
    for (int it = 0; it < 4; ++it)
        #pragma unroll
        for (int ks = 0; ks < 4; ++ks)
            w0f[it][ks] = *(const bf16x8*)(w0p + (it*4+ks)*1024);
    #pragma unroll
    for (int it = 0; it < 4; ++it)
        #pragma unroll
        for (int ks = 0; ks < 2; ++ks)
            w1f[it][ks] = *(const bf16x8*)(w1p + (it*2+ks)*1024);

    // ---- w2 -> f16 pairs matching C-layout: w2h[o][it][p], p = reg-pair ----
    f16x2 w2h[2][4][2];
    #pragma unroll
    for (int o = 0; o < 2; ++o)
        #pragma unroll
        for (int it = 0; it < 4; ++it) {
            f32x4 v = *(const f32x4*)(w2 + t*128 + o*64 + it*16 + lq*4);
            w2h[o][it][0] = __builtin_amdgcn_cvt_pkrtz(v[0], v[1]);
            w2h[o][it][1] = __builtin_amdgcn_cvt_pkrtz(v[2], v[3]);
        }

    // ---- bias pointers (loop-invariant; loaded per iter into C-operand) ----
    const float* b0p = b0 + t*64 + lq*4;
    const float* b1p = b1 + t*64 + lq*4;
    const float2 b2v = *(const float2*)(b2 + t*2);

    // ---- x fragments (wave's 16-row slice); preload iter 0 ----
    const unsigned char* xq = ws + XB_OFF + (size_t)(g*32 + w)*4096 + lane*16;
    bf16x8 xf[4];
    #pragma unroll
    for (int ks = 0; ks < 4; ++ks)
        xf[ks] = *(const bf16x8*)(xq + ks*1024);

    unsigned char* hb = hsm + w*2048;                       // this wave's 2 bricks
    const int wboff = ((lq >> 1) * 16 + lr) * 16 + (lq & 1) * 8;

    for (int s = 0; s < 8; ++s) {
        // ======== layer 0: D0[i][row] = w0m @ x^T, C-init = b0 loads ========
        f32x4 acc[4];
        #pragma unroll
        for (int it = 0; it < 4; ++it)
            acc[it] = *(const f32x4*)(b0p + it*16);
        #pragma unroll
        for (int ks = 0; ks < 4; ++ks)
            #pragma unroll
            for (int it = 0; it < 4; ++it)
                acc[it] = __builtin_amdgcn_mfma_f32_16x16x32_bf16(
                              w0f[it][ks], xf[ks], acc[it], 0, 0, 0);

        // xf dead: prefetch next tile (clamped; uniform offset -> scalar addr)
        {
            const unsigned char* xn = xq + (s < 7 ? (s + 1) : 7) * 16384;
            #pragma unroll
            for (int ks = 0; ks < 4; ++ks)
                xf[ks] = *(const bf16x8*)(xn + ks*1024);
        }

        // ======== epi0: leaky + cvt -> h bricks (4 x b64) ========
        #pragma unroll
        for (int it = 0; it < 4; ++it) {
            union { bf16_t h[4]; unsigned long long u; } pk;
            #pragma unroll
            for (int r = 0; r < 4; ++r) {
                float u = acc[it][r];
                pk.h[r] = (bf16_t)fmaxf(u, LEAKY * u);
            }
            *(unsigned long long*)(hb + (it>>1)*1024 + (it&1)*512 + wboff) = pk.u;
        }

        // ======== layer 1: D1[i2][row] = w1 @ h^T, C-init = b1 loads ========
        bf16x8 hf0 = *(const bf16x8*)(hb + lane*16);
        bf16x8 hf1 = *(const bf16x8*)(hb + 1024 + lane*16);
        #pragma unroll
        for (int it = 0; it < 4; ++it)
            acc[it] = *(const f32x4*)(b1p + it*16);        // acc0 dead, reuse
        #pragma unroll
        for (int it = 0; it < 4; ++it) {
            acc[it] = __builtin_amdgcn_mfma_f32_16x16x32_bf16(
                          w1f[it][0], hf0, acc[it], 0, 0, 0);
            acc[it] = __builtin_amdgcn_mfma_f32_16x16x32_bf16(
                          w1f[it][1], hf1, acc[it], 0, 0, 0);
        }

        // ======== layer 2: leaky -> f16 pairs -> dot2 + quad reduce ========
        float p0 = 0.f, p1 = 0.f;
        #pragma unroll
        for (int it = 0; it < 4; ++it) {
            #pragma unroll
            for (int p = 0; p < 2; ++p) {
                float u0 = acc[it][2*p],   v0 = fmaxf(u0, LEAKY * u0);
                float u1 = acc[it][2*p+1], v1 = fmaxf(u1, LEAKY * u1);
                f16x2 hh = __builtin_amdgcn_cvt_pkrtz(v0, v1);
                p0 = __builtin_amdgcn_fdot2(w2h[0][it][p], hh, p0, false);
                p1 = __builtin_amdgcn_fdot2(w2h[1][it][p], hh, p1, false);
            }
        }
        p0 += __shfl_xor(p0, 16); p0 += __shfl_xor(p0, 32);
        p1 += __shfl_xor(p1, 16); p1 += __shfl_xor(p1, 32);
        if (lq == 0) {
            int row = g*512 + s*64 + w*16 + lr;
            float2 o2 = { p0 + b2v.x, p1 + b2v.y };
            *(float2*)(out + (size_t)row*256 + t*2) = o2;
        }
    }
}

extern "C" void kernel_launch(void* const* d_in, const int* in_sizes, int n_in,
                              void* d_out, int out_size, void* d_ws, size_t ws_size,
                              hipStream_t stream) {
    const float* x  = (const float*)d_in[0];
    const float* w0 = (const float*)d_in[1];
    const float* w1 = (const float*)d_in[2];
    const float* w2 = (const float*)d_in[3];
    const float* b0 = (const float*)d_in[4];
    const float* b1 = (const float*)d_in[5];
    const float* b2 = (const float*)d_in[6];
    unsigned char* ws = (unsigned char*)d_ws;   // needs 5120 KiB
    float* out = (float*)d_out;

    // 5120 bricks, one wave each, 4 waves/block
    brickify<<<dim3(1280), dim3(256), 0, stream>>>(x, w0, w1, ws);
    // grid (16 batch super-groups x 128 t) = 2048 blocks, 4 waves each.
    fused_mlp<<<dim3(16, 128), dim3(256), 0, stream>>>(ws, w2, b0, b1, b2, out);
}